// Round 5
// baseline (701.563 us; speedup 1.0000x reference)
//
#include <hip/hip_runtime.h>
#include <math.h>

// ---------------------------------------------------------------------------
// Transformer-XL RelPartialLearnableDecoderLayer.
// Round 5: barrier-free per-wave flash attention (wave-private LDS, direct
// global MFMA fragments), GEMM epilogue fusion of GRU gates (z/rx and final
// gate combine inside GEMMs), split-A GEMM, 15 dispatches total.
// rel_shift closed form: BD[i,j] = BD_raw[i, j+511-i]; mask j > i+512.
// ---------------------------------------------------------------------------

#define QLEN 512
#define MLEN 512
#define KLEN 1024
#define BSZ  4
#define DM   1024
#define DI   4096
#define NH   16
#define DH   64
#define HC   (3*DM)
#define HR   (KLEN*BSZ)   // 4096
#define NROWS (QLEN*BSZ)  // 2048

enum { ACT_NONE = 0, ACT_RELU = 1, ACT_SIG = 2, ACT_TANH = 3 };
enum { MODE_NORM = 0, MODE_QKV = 1, MODE_RK = 2, MODE_ZR = 3, MODE_GOUT = 4 };

using short8 = __attribute__((ext_vector_type(8))) short;
using f32x4  = __attribute__((ext_vector_type(4))) float;

__device__ __forceinline__ unsigned short f2bf(float f) {
  union { float f; unsigned u; } v;
  v.f = f;
  unsigned r = v.u + 0x7FFFu + ((v.u >> 16) & 1u);  // RNE
  return (unsigned short)(r >> 16);
}
__device__ __forceinline__ float bf2f(unsigned short u) {
  union { unsigned u; float f; } v;
  v.u = ((unsigned)u) << 16;
  return v.f;
}

__device__ __forceinline__ void async16(const void* g, void* l) {
  __builtin_amdgcn_global_load_lds(
      (const __attribute__((address_space(1))) void*)g,
      (__attribute__((address_space(3))) void*)l, 16, 0, 0);
}

__device__ __forceinline__ float waveSum(float v) {
#pragma unroll
  for (int o = 32; o; o >>= 1) v += __shfl_down(v, o, 64);
  return v;
}

// ---------------- LayerNorm -> bf16 (optional raw bf16 copy) ----------------
template <bool CONCAT, bool RAW>
__global__ __launch_bounds__(256) void ln_kernel(
    const float* __restrict__ a, const float* __restrict__ a2,
    const float* __restrict__ wt, const float* __restrict__ bs,
    unsigned short* __restrict__ dst, unsigned short* __restrict__ rawdst) {
  const int row = blockIdx.x;
  const int tid = threadIdx.x;
  const float* srow;
  if (CONCAT)
    srow = (row < MLEN * BSZ) ? a + (size_t)row * DM
                              : a2 + (size_t)(row - MLEN * BSZ) * DM;
  else
    srow = a + (size_t)row * DM;
  float4 x = *(const float4*)(srow + tid * 4);
  if constexpr (RAW) {
    ushort4 rw = {f2bf(x.x), f2bf(x.y), f2bf(x.z), f2bf(x.w)};
    *(ushort4*)(rawdst + (size_t)row * DM + tid * 4) = rw;
  }
  float s = x.x + x.y + x.z + x.w;
  float q = x.x * x.x + x.y * x.y + x.z * x.z + x.w * x.w;
  __shared__ float2 red[4];
  float2 p;
  p.x = waveSum(s);
  p.y = waveSum(q);
  if ((tid & 63) == 0) red[tid >> 6] = p;
  __syncthreads();
  float S = red[0].x + red[1].x + red[2].x + red[3].x;
  float Q = red[0].y + red[1].y + red[2].y + red[3].y;
  const float inv = 1.0f / DM;
  float mu = S * inv;
  float var = Q * inv - mu * mu;
  float rs = rsqrtf(var + 1e-5f);
  float4 w4 = *(const float4*)(wt + tid * 4);
  float4 b4 = *(const float4*)(bs + tid * 4);
  ushort4 o = {f2bf((x.x - mu) * rs * w4.x + b4.x),
               f2bf((x.y - mu) * rs * w4.y + b4.y),
               f2bf((x.z - mu) * rs * w4.z + b4.z),
               f2bf((x.w - mu) * rs * w4.w + b4.w)};
  *(ushort4*)(dst + (size_t)row * DM + tid * 4) = o;
}

// ---------------- bf16 MFMA GEMM with fused epilogues ----------------------
// A (or A0|A1 halves when SPLIT, each row-major stride 1024): M x K bf16.
// Bt: N x K bf16 row-major (B^T).
// MODE_NORM: C = act(A@Bt^T [+bias]) -> Cv (bf16 if OUT16 else fp32, ldc);
//            if xsrc&&g0: also g0[m][c] = bf16(xsrc[m][c]) (x-cast copy).
// MODE_QKV:  scatter heads into Q_g/K_g/V_gT (g0/g1/g2).
// MODE_RK:   scatter rk into g0.
// MODE_ZR:   col<1024: zbuf=Cv fp32 <- sigmoid(v+bias);
//            col>=1024: g0 bf16 <- sigmoid(v) * xsrc[m][col-1024].
// MODE_GOUT: h=tanh(v); Cv fp32 <- (1-z)*x + z*h, z=zsrc, x=xsrc.
template <int BM, int ACT, bool BIAS, int MODE, bool OUT16, bool SPLIT>
__global__ __launch_bounds__(256) void mgemm(
    const unsigned short* __restrict__ A0, const unsigned short* __restrict__ A1,
    const unsigned short* __restrict__ Bt, void* __restrict__ Cv,
    const float* __restrict__ bias, const float* __restrict__ xsrc,
    unsigned short* __restrict__ g0, unsigned short* __restrict__ g1,
    unsigned short* __restrict__ g2, const float* __restrict__ zsrc,
    int K, int ldc) {
  constexpr int TM = (BM == 128) ? 4 : 1;
  constexpr int TN = (BM == 128) ? 4 : 8;
  __shared__ __align__(16) unsigned short As[BM][32];
  __shared__ __align__(16) unsigned short Bs[128][32];
  const int tid = threadIdx.x;
  const int wave = tid >> 6, lane = tid & 63;
  const int row0 = blockIdx.y * BM, col0 = blockIdx.x * 128;
  const int wm = (BM == 128) ? (wave >> 1) * 64 : wave * 16;
  const int wn = (BM == 128) ? (wave & 1) * 64 : 0;
  const int lr = lane & 15, quad = lane >> 4;

  const int sr = lane >> 2, sc = (lane & 3) * 8;
  const int arow = row0 + ((BM == 128) ? wave * 32 : wave * 16) + sr;
  const unsigned short* gb = Bt + (size_t)(col0 + wave * 32 + sr) * K + sc;
  const size_t rstepB = (size_t)16 * K;
  unsigned short* lb0 = &Bs[wave * 32][0];
  unsigned short* lb1 = &Bs[wave * 32 + 16][0];
  unsigned short* la0 = (BM == 128) ? &As[wave * 32][0] : &As[wave * 16][0];
  unsigned short* la1 = (BM == 128) ? &As[wave * 32 + 16][0] : nullptr;

  f32x4 acc[TM][TN];
#pragma unroll
  for (int a = 0; a < TM; a++)
#pragma unroll
    for (int b = 0; b < TN; b++) {
      acc[a][b][0] = 0.f; acc[a][b][1] = 0.f;
      acc[a][b][2] = 0.f; acc[a][b][3] = 0.f;
    }

  const unsigned short* const Asegs[2] = {A0, A1};
#pragma unroll
  for (int seg = 0; seg < (SPLIT ? 2 : 1); seg++) {
    const int segK = SPLIT ? 1024 : K;
    const int astr = SPLIT ? 1024 : K;
    const unsigned short* ga = Asegs[seg] + (size_t)arow * astr + sc;
    const size_t rstepA = (size_t)16 * astr;
    for (int k0 = 0; k0 < segK; k0 += 32) {
      __syncthreads();
      async16(ga, la0);
      if constexpr (BM == 128) async16(ga + rstepA, la1);
      async16(gb, lb0);
      async16(gb + rstepB, lb1);
      ga += 32;
      gb += 32;
      __syncthreads();
      short8 af[TM], bf[TN];
#pragma unroll
      for (int mi = 0; mi < TM; mi++)
        af[mi] = *(const short8*)&As[wm + mi * 16 + lr][quad * 8];
#pragma unroll
      for (int ni = 0; ni < TN; ni++)
        bf[ni] = *(const short8*)&Bs[wn + ni * 16 + lr][quad * 8];
#pragma unroll
      for (int mi = 0; mi < TM; mi++)
#pragma unroll
        for (int ni = 0; ni < TN; ni++)
          acc[mi][ni] = __builtin_amdgcn_mfma_f32_16x16x32_bf16(
              af[mi], bf[ni], acc[mi][ni], 0, 0, 0);
    }
  }

  const int cbase = col0 + wn + lr;
  float bv[TN];
  if constexpr (BIAS) {
#pragma unroll
    for (int ni = 0; ni < TN; ni++) bv[ni] = bias[cbase + ni * 16];
  }
  const int region = (MODE == MODE_QKV || MODE == MODE_ZR) ? (col0 >> 10) : 0;
#pragma unroll
  for (int mi = 0; mi < TM; mi++) {
    const int r0 = row0 + wm + mi * 16 + quad * 4;
#pragma unroll
    for (int ni = 0; ni < TN; ni++) {
      const int cc = cbase + ni * 16;
#pragma unroll
      for (int e = 0; e < 4; e++) {
        float v = acc[mi][ni][e];
        if constexpr (BIAS) v += bv[ni];
        if constexpr (ACT == ACT_RELU) v = fmaxf(v, 0.f);
        else if constexpr (ACT == ACT_SIG) v = 1.f / (1.f + expf(-v));
        else if constexpr (ACT == ACT_TANH) v = tanhf(v);
        if constexpr (MODE == MODE_QKV) {
          const int rr = r0 + e;
          const int pos = rr >> 2, bb = rr & 3;
          const int cl = cc & 1023, hn = cl >> 6, d = cl & 63;
          const unsigned short hv = f2bf(v);
          if (region == 0) {
            if (pos >= MLEN)
              g0[(((size_t)(bb * NH + hn) * QLEN + (pos - MLEN)) << 6) + d] = hv;
          } else if (region == 1) {
            g1[(((size_t)(bb * NH + hn) * KLEN + pos) << 6) + d] = hv;
          } else {
            g2[(((size_t)(bb * NH + hn) * DH + d) << 10) + pos] = hv;
          }
        } else if constexpr (MODE == MODE_RK) {
          const int hn = cc >> 6, d = cc & 63;
          g0[(((size_t)hn * KLEN + (r0 + e)) << 6) + d] = f2bf(v);
        } else if constexpr (MODE == MODE_ZR) {
          const float sg = 1.f / (1.f + expf(-v));
          if (region == 0) {
            ((float*)Cv)[(size_t)(r0 + e) * 1024 + cc] = sg;
          } else {
            const int c1 = cc - 1024;
            g0[(size_t)(r0 + e) * 1024 + c1] =
                f2bf(sg * xsrc[(size_t)(r0 + e) * 1024 + c1]);
          }
        } else if constexpr (MODE == MODE_GOUT) {
          const float h = tanhf(v);
          const float z = zsrc[(size_t)(r0 + e) * 1024 + cc];
          const float xv = xsrc[(size_t)(r0 + e) * 1024 + cc];
          ((float*)Cv)[(size_t)(r0 + e) * 1024 + cc] =
              (1.f - z) * xv + z * h;
        } else {
          if constexpr (OUT16)
            ((unsigned short*)Cv)[(size_t)(r0 + e) * ldc + cc] = f2bf(v);
          else
            ((float*)Cv)[(size_t)(r0 + e) * ldc + cc] = v;
        }
      }
      if constexpr (MODE == MODE_NORM) {
        if (xsrc && g0) {
#pragma unroll
          for (int e = 0; e < 4; e++)
            g0[(size_t)(r0 + e) * 1024 + cc] =
                f2bf(xsrc[(size_t)(r0 + e) * 1024 + cc]);
        }
      }
    }
  }
}

// ---------------- barrier-free per-wave flash attention --------------------
// grid (8,16,4) x 256 thr; wave w owns Q-rows i0w = bx*64 + w*16 and runs a
// fully independent j-loop. MFMA B-fragments (K/V/rk) load directly from the
// dense per-head global buffers (L2-hot). LDS is wave-private (P transpose +
// BD 2-tile ring) -> NO __syncthreads in the kernel.
// Window math (16-row tiles): off = (j0+496-i0w)%64 + 15 + jl - il, tile =
// L0+t+(off>>6) with L0=(496-i0w)>>6; ring slot = tile&1. Out-of-range tiles
// are provably masked (off>=64 & tile>=16  <=>  j > i+512).
#define PT 76
__global__ __launch_bounds__(256) void fused_attn(
    const unsigned short* __restrict__ Q_g,   // [b][n][512][64]
    const unsigned short* __restrict__ K_g,   // [b][n][1024][64]
    const unsigned short* __restrict__ V_gT,  // [b][n][64][1024]
    const unsigned short* __restrict__ rk_g,  // [n][1024][64]
    const float* __restrict__ rwb, const float* __restrict__ rrb,
    unsigned short* __restrict__ attnb,       // [2048][1024] bf16
    float* __restrict__ ent) {
  const int n = blockIdx.y, b = blockIdx.z;
  const int tid = threadIdx.x;
  const int wave = tid >> 6, lane = tid & 63;
  const int lr = lane & 15, quad = lane >> 4;
  const int i0w = blockIdx.x * 64 + wave * 16;

  __shared__ __align__(16) unsigned short PtS[4][16][PT];
  __shared__ __align__(16) unsigned short BDS[4][2][16][PT];
  unsigned short (*Ptw)[PT] = PtS[wave];
  unsigned short (*Bw)[16][PT] = BDS[wave];

  const unsigned short* Qb = Q_g + (((size_t)(b * NH + n) * QLEN + i0w) << 6);
  const unsigned short* Kb = K_g + (((size_t)(b * NH + n) * KLEN) << 6);
  const unsigned short* Vb = V_gT + (((size_t)(b * NH + n) * DH) << 10);
  const unsigned short* Rb = rk_g + (((size_t)n * KLEN) << 6);

  // Q A-fragments (rows = lr) with both biases pre-added, loop-invariant.
  short8 aw[2], aq[2];
#pragma unroll
  for (int ks = 0; ks < 2; ks++) {
    short8 q = *(const short8*)(Qb + lr * 64 + ks * 32 + quad * 8);
#pragma unroll
    for (int j = 0; j < 8; j++) {
      const float f = bf2f((unsigned short)q[j]);
      const int d = ks * 32 + quad * 8 + j;
      aw[ks][j] = (short)f2bf(f + rwb[n * DH + d]);
      aq[ks][j] = (short)f2bf(f + rrb[n * DH + d]);
    }
  }

  const int L0 = (496 - i0w) >> 6;
  // pre-loop BD tile L0 -> ring slot L0&1
  {
    f32x4 bd[4];
#pragma unroll
    for (int ni = 0; ni < 4; ni++) {
      bd[ni][0] = 0.f; bd[ni][1] = 0.f; bd[ni][2] = 0.f; bd[ni][3] = 0.f;
    }
#pragma unroll
    for (int ks = 0; ks < 2; ks++)
#pragma unroll
      for (int ni = 0; ni < 4; ni++) {
        short8 rf = *(const short8*)(Rb + ((L0 * 64 + ni * 16 + lr) << 6) +
                                     ks * 32 + quad * 8);
        bd[ni] = __builtin_amdgcn_mfma_f32_16x16x32_bf16(aq[ks], rf, bd[ni],
                                                         0, 0, 0);
      }
#pragma unroll
    for (int ni = 0; ni < 4; ni++)
#pragma unroll
      for (int e = 0; e < 4; e++)
        Bw[L0 & 1][quad * 4 + e][ni * 16 + lr] = f2bf(bd[ni][e]);
  }

  f32x4 O[4];
#pragma unroll
  for (int d = 0; d < 4; d++) {
    O[d][0] = 0.f; O[d][1] = 0.f; O[d][2] = 0.f; O[d][3] = 0.f;
  }
  float mrow[4] = {-INFINITY, -INFINITY, -INFINITY, -INFINITY};
  float lrow[4] = {0.f, 0.f, 0.f, 0.f};
  float erow[4] = {0.f, 0.f, 0.f, 0.f};

  const int nj = ((i0w + 527) >> 6) + 1;
  for (int t = 0; t < nj; t++) {
    const int j0 = t * 64;
    const int H = L0 + t + 1;
    // ---- issue all global fragment loads for this tile up front ----
    short8 kf[2][4], vf[2][4], rf[2][4];
#pragma unroll
    for (int ks = 0; ks < 2; ks++)
#pragma unroll
      for (int ni = 0; ni < 4; ni++)
        kf[ks][ni] = *(const short8*)(Kb + ((j0 + ni * 16 + lr) << 6) +
                                      ks * 32 + quad * 8);
#pragma unroll
    for (int ks = 0; ks < 2; ks++)
#pragma unroll
      for (int d = 0; d < 4; d++)
        vf[ks][d] = *(const short8*)(Vb + (((size_t)(d * 16 + lr)) << 10) +
                                     j0 + ks * 32 + quad * 8);
    if (H < 16) {
#pragma unroll
      for (int ks = 0; ks < 2; ks++)
#pragma unroll
        for (int ni = 0; ni < 4; ni++)
          rf[ks][ni] = *(const short8*)(Rb + ((H * 64 + ni * 16 + lr) << 6) +
                                        ks * 32 + quad * 8);
    }
    // ---- AC + new BD tile MFMA ----
    f32x4 ac[4], bd[4];
#pragma unroll
    for (int ni = 0; ni < 4; ni++) {
      ac[ni][0] = 0.f; ac[ni][1] = 0.f; ac[ni][2] = 0.f; ac[ni][3] = 0.f;
      bd[ni][0] = 0.f; bd[ni][1] = 0.f; bd[ni][2] = 0.f; bd[ni][3] = 0.f;
    }
#pragma unroll
    for (int ks = 0; ks < 2; ks++)
#pragma unroll
      for (int ni = 0; ni < 4; ni++)
        ac[ni] = __builtin_amdgcn_mfma_f32_16x16x32_bf16(aw[ks], kf[ks][ni],
                                                         ac[ni], 0, 0, 0);
    if (H < 16) {
#pragma unroll
      for (int ks = 0; ks < 2; ks++)
#pragma unroll
        for (int ni = 0; ni < 4; ni++)
          bd[ni] = __builtin_amdgcn_mfma_f32_16x16x32_bf16(aq[ks], rf[ks][ni],
                                                           bd[ni], 0, 0, 0);
#pragma unroll
      for (int ni = 0; ni < 4; ni++)
#pragma unroll
        for (int e = 0; e < 4; e++)
          Bw[H & 1][quad * 4 + e][ni * 16 + lr] = f2bf(bd[ni][e]);
    }
    // ---- scores: AC + rel-shifted BD, mask, scale ----
    const int sbase = ((j0 + 496 - i0w) & 63) + 15;
    float scv[4][4];
#pragma unroll
    for (int ni = 0; ni < 4; ni++) {
      const int jl = ni * 16 + lr;
#pragma unroll
      for (int e = 0; e < 4; e++) {
        const int il = quad * 4 + e;
        const int off = sbase + jl - il;                 // [0,126]
        const int tile = L0 + t + (off >> 6);
        const float bdv = bf2f(Bw[tile & 1][il][off & 63]);
        const bool masked = (j0 + jl) > (i0w + il + MLEN);
        scv[ni][e] = masked ? -INFINITY : (ac[ni][e] + bdv) * 0.125f;
      }
    }
    // ---- online softmax over the 16 col-lanes of each quad ----
#pragma unroll
    for (int e = 0; e < 4; e++) {
      const int il = quad * 4 + e;
      float tm = fmaxf(fmaxf(scv[0][e], scv[1][e]),
                       fmaxf(scv[2][e], scv[3][e]));
#pragma unroll
      for (int msk = 1; msk < 16; msk <<= 1)
        tm = fmaxf(tm, __shfl_xor(tm, msk, 64));
      const float mo = mrow[e];
      const float mn = fmaxf(mo, tm);
      const float al = __expf(mo - mn);
      float psum = 0.f, pes = 0.f, ps[4];
#pragma unroll
      for (int ni = 0; ni < 4; ni++) {
        const float s_ = scv[ni][e];
        const float p = __expf(s_ - mn);
        ps[ni] = p;
        psum += p;
        pes += (p > 0.f) ? p * s_ : 0.f;
      }
#pragma unroll
      for (int msk = 1; msk < 16; msk <<= 1) {
        psum += __shfl_xor(psum, msk, 64);
        pes += __shfl_xor(pes, msk, 64);
      }
      lrow[e] = lrow[e] * al + psum;
      erow[e] = erow[e] * al + pes;
      mrow[e] = mn;
#pragma unroll
      for (int d = 0; d < 4; d++) O[d][e] *= al;
#pragma unroll
      for (int ni = 0; ni < 4; ni++)
        Ptw[il][ni * 16 + lr] = f2bf(ps[ni]);
    }
    // ---- PV MFMA (wave-private P roundtrip; V frags already in regs) ----
#pragma unroll
    for (int ks = 0; ks < 2; ks++) {
      short8 ap = *(const short8*)&Ptw[lr][ks * 32 + quad * 8];
#pragma unroll
      for (int d = 0; d < 4; d++)
        O[d] = __builtin_amdgcn_mfma_f32_16x16x32_bf16(ap, vf[ks][d], O[d],
                                                       0, 0, 0);
    }
  }

  // ---- epilogue: normalize, store, entropy (one atomic per wave) ----
#pragma unroll
  for (int e = 0; e < 4; e++) {
    const int il = quad * 4 + e;
    const float invl = 1.f / lrow[e];
#pragma unroll
    for (int d = 0; d < 4; d++)
      attnb[((size_t)(i0w + il) * BSZ + b) * DM + n * DH + d * 16 + lr] =
          f2bf(O[d][e] * invl);
  }
  float esum = 0.f;
#pragma unroll
  for (int e = 0; e < 4; e++)
    esum += mrow[e] + __logf(lrow[e]) - erow[e] / lrow[e];
  esum = (lr == 0) ? esum : 0.f;
  esum = waveSum(esum);
  if (lane == 0) atomicAdd(ent + n, esum * (1.f / (QLEN * BSZ)));
}

// ---------------- batched weight cast+transpose ----------------
#define MAXD 18
struct TDesc {
  const float* src;
  unsigned short* dst;
  int N, dstStride, colOff, tilesX, tileBase;
};
struct TDescs { TDesc d[MAXD]; int n; };

__global__ __launch_bounds__(256) void castT_batch(TDescs ds) {
  const int bid = blockIdx.x;
  int di = 0;
  while (di + 1 < ds.n && ds.d[di + 1].tileBase <= bid) di++;
  const TDesc t = ds.d[di];
  const int lt = bid - t.tileBase;
  const int n0 = (lt % t.tilesX) * 64, k0 = (lt / t.tilesX) * 64;
  __shared__ float T[64][65];
  const int tid = threadIdx.x;
  const int tx = tid & 15, ty = tid >> 4;
#pragma unroll
  for (int l = 0; l < 4; l++) {
    const int k = ty + l * 16;
    float4 v = *(const float4*)(t.src + (size_t)(k0 + k) * t.N + n0 + tx * 4);
    T[tx * 4 + 0][k] = v.x;
    T[tx * 4 + 1][k] = v.y;
    T[tx * 4 + 2][k] = v.z;
    T[tx * 4 + 3][k] = v.w;
  }
  __syncthreads();
#pragma unroll
  for (int l = 0; l < 4; l++) {
    const int n = ty + l * 16;
    ushort4 o = {f2bf(T[n][tx * 4 + 0]), f2bf(T[n][tx * 4 + 1]),
                 f2bf(T[n][tx * 4 + 2]), f2bf(T[n][tx * 4 + 3])};
    *(ushort4*)(t.dst + (size_t)(n0 + n) * t.dstStride + t.colOff + k0 +
                tx * 4) = o;
  }
}

// ---------------- fp32 -> bf16 row cast ----------------
__global__ __launch_bounds__(256) void castRows(
    const float* __restrict__ src, unsigned short* __restrict__ dst) {
  const size_t e0 = ((size_t)blockIdx.x * 256 + threadIdx.x) * 4;
  float4 v = *(const float4*)(src + e0);
  ushort4 o = {f2bf(v.x), f2bf(v.y), f2bf(v.z), f2bf(v.w)};
  *(ushort4*)(dst + e0) = o;
}

__global__ void misc_init(const float* __restrict__ gmbz,
                          const float* __restrict__ gpbz,
                          float* __restrict__ bias_gm,
                          float* __restrict__ bias_gp,
                          float* __restrict__ ent) {
  const int i = blockIdx.x * 256 + threadIdx.x;
  if (i < 2048) {
    bias_gm[i] = (i < 1024) ? gmbz[i] : 0.f;
    bias_gp[i] = (i < 1024) ? gpbz[i] : 0.f;
  }
  if (i < 16) ent[i] = 0.f;
}

// ---------------------------------------------------------------------------
extern "C" void kernel_launch(void* const* d_in, const int* in_sizes, int n_in,
                              void* d_out, int out_size, void* d_ws,
                              size_t ws_size, hipStream_t stream) {
  (void)in_sizes; (void)n_in; (void)out_size; (void)ws_size;
  const float* w      = (const float*)d_in[0];
  const float* mems   = (const float*)d_in[1];
  const float* r      = (const float*)d_in[2];
  const float* rwb    = (const float*)d_in[3];
  const float* rrb    = (const float*)d_in[4];
  const float* ln_a_w = (const float*)d_in[6];
  const float* ln_a_b = (const float*)d_in[7];
  const float* W_qkv  = (const float*)d_in[8];
  const float* W_r    = (const float*)d_in[9];
  const float* W_o    = (const float*)d_in[10];
  const float* ln2_w  = (const float*)d_in[11];
  const float* ln2_b  = (const float*)d_in[12];
  const float* ff_W1  = (const float*)d_in[13];
  const float* ff_b1  = (const float*)d_in[14];
  const float* ff_W2  = (const float*)d_in[15];
  const float* ff_b2  = (const float*)d_in[16];
  const float* gm_Wr  = (const float*)d_in[17];
  const float* gm_Ur  = (const float*)d_in[18];
  const float* gm_Uz  = (const float*)d_in[19];
  const float* gm_Wg  = (const float*)d_in[20];
  const float* gm_Ug  = (const float*)d_in[21];
  const float* gm_Wz  = (const float*)d_in[22];
  const float* gm_bz  = (const float*)d_in[23];
  const float* gp_Wr  = (const float*)d_in[24];
  const float* gp_Ur  = (const float*)d_in[25];
  const float* gp_Uz  = (const float*)d_in[26];
  const float* gp_Wg  = (const float*)d_in[27];
  const float* gp_Ug  = (const float*)d_in[28];
  const float* gp_Wz  = (const float*)d_in[29];
  const float* gp_bz  = (const float*)d_in[30];

  float* out = (float*)d_out;
  float* ent = out + (size_t)NROWS * DM;

  // ---- workspace carve (bytes) ----
  char* base = (char*)d_ws;
  size_t o = 0;
  unsigned short* wt_qkv   = (unsigned short*)(base + o); o += (size_t)3072 * 1024 * 2;
  unsigned short* wt_r     = (unsigned short*)(base + o); o += (size_t)1024 * 1024 * 2;
  unsigned short* wt_o     = (unsigned short*)(base + o); o += (size_t)1024 * 1024 * 2;
  unsigned short* wt_gm_zr = (unsigned short*)(base + o); o += (size_t)2048 * 2048 * 2;
  unsigned short* wt_gm_g  = (unsigned short*)(base + o); o += (size_t)1024 * 2048 * 2;
  unsigned short* wt_gp_zr = (unsigned short*)(base + o); o += (size_t)2048 * 2048 * 2;
  unsigned short* wt_gp_g  = (unsigned short*)(base + o); o += (size_t)1024 * 2048 * 2;
  unsigned short* wt_ff1   = (unsigned short*)(base + o); o += (size_t)4096 * 1024 * 2;
  unsigned short* wt_ff2   = (unsigned short*)(base + o); o += (size_t)1024 * 4096 * 2;
  float* bias_gm = (float*)(base + o); o += 2048 * 4;
  float* bias_gp = (float*)(base + o); o += 2048 * 4;
  unsigned short* Q_g  = (unsigned short*)(base + o); o += (size_t)BSZ * NH * QLEN * DH * 2;
  unsigned short* K_g  = (unsigned short*)(base + o); o += (size_t)BSZ * NH * KLEN * DH * 2;
  unsigned short* V_gT = (unsigned short*)(base + o); o += (size_t)BSZ * NH * DH * KLEN * 2;
  unsigned short* rk_g = (unsigned short*)(base + o); o += (size_t)NH * KLEN * DH * 2;
  unsigned short* lncat_bf = (unsigned short*)(base + o); o += (size_t)HR * DM * 2;
  unsigned short* r_bf  = (unsigned short*)(base + o); o += (size_t)KLEN * DM * 2;
  unsigned short* attnb_bf = (unsigned short*)(base + o); o += (size_t)NROWS * DM * 2;
  unsigned short* ybuf  = (unsigned short*)(base + o); o += (size_t)NROWS * DM * 2;
  unsigned short* xw_bf = (unsigned short*)(base + o); o += (size_t)NROWS * DM * 2;
  unsigned short* rxbuf = (unsigned short*)(base + o); o += (size_t)NROWS * DM * 2;
  unsigned short* o1_bf = (unsigned short*)(base + o); o += (size_t)NROWS * DM * 2;
  unsigned short* lnb_bf = (unsigned short*)(base + o); o += (size_t)NROWS * DM * 2;
  unsigned short* ffh_bf = (unsigned short*)(base + o); o += (size_t)NROWS * DI * 2;
  float* zbuf = (float*)(base + o); o += (size_t)NROWS * DM * 4;
  float* o1f  = (float*)(base + o); o += (size_t)NROWS * DM * 4;

  // ---- phase 0: batched weight transposes + misc init ----
  TDescs ds;
  int nt = 0, tb = 0;
  auto add = [&](const float* s, unsigned short* d, int N, int K, int stride,
                 int colOff) {
    ds.d[nt] = {s, d, N, stride, colOff, N / 64, tb};
    tb += (N / 64) * (K / 64);
    nt++;
  };
  add(W_qkv, wt_qkv, 3072, 1024, 1024, 0);
  add(W_r, wt_r, 1024, 1024, 1024, 0);
  add(W_o, wt_o, 1024, 1024, 1024, 0);
  add(gm_Wz, wt_gm_zr, 1024, 1024, 2048, 0);
  add(gm_Uz, wt_gm_zr, 1024, 1024, 2048, 1024);
  add(gm_Wr, wt_gm_zr + (size_t)1024 * 2048, 1024, 1024, 2048, 0);
  add(gm_Ur, wt_gm_zr + (size_t)1024 * 2048, 1024, 1024, 2048, 1024);
  add(gm_Wg, wt_gm_g, 1024, 1024, 2048, 0);
  add(gm_Ug, wt_gm_g, 1024, 1024, 2048, 1024);
  add(gp_Wz, wt_gp_zr, 1024, 1024, 2048, 0);
  add(gp_Uz, wt_gp_zr, 1024, 1024, 2048, 1024);
  add(gp_Wr, wt_gp_zr + (size_t)1024 * 2048, 1024, 1024, 2048, 0);
  add(gp_Ur, wt_gp_zr + (size_t)1024 * 2048, 1024, 1024, 2048, 1024);
  add(gp_Wg, wt_gp_g, 1024, 1024, 2048, 0);
  add(gp_Ug, wt_gp_g, 1024, 1024, 2048, 1024);
  add(ff_W1, wt_ff1, 4096, 1024, 1024, 0);
  add(ff_W2, wt_ff2, 1024, 4096, 4096, 0);
  ds.n = nt;
  castT_batch<<<tb, 256, 0, stream>>>(ds);
  misc_init<<<8, 256, 0, stream>>>(gm_bz, gp_bz, bias_gm, bias_gp, ent);

  // ---- phase 1: LN + QKV / r projections (per-head dense outputs) ----
  ln_kernel<true, false><<<HR, 256, 0, stream>>>(mems, w, ln_a_w, ln_a_b,
                                                 lncat_bf, nullptr);
  mgemm<128, ACT_NONE, false, MODE_QKV, true, false>
      <<<dim3(24, 32), 256, 0, stream>>>(lncat_bf, nullptr, wt_qkv, nullptr,
                                         nullptr, nullptr, Q_g, K_g, V_gT,
                                         nullptr, 1024, 0);
  castRows<<<1024, 256, 0, stream>>>(r, r_bf);
  mgemm<64, ACT_NONE, false, MODE_RK, true, false>
      <<<dim3(8, 16), 256, 0, stream>>>(r_bf, nullptr, wt_r, nullptr, nullptr,
                                        nullptr, rk_g, nullptr, nullptr,
                                        nullptr, 1024, 0);

  // ---- phase 2: fused attention (barrier-free) ----
  fused_attn<<<dim3(8, NH, BSZ), 256, 0, stream>>>(Q_g, K_g, V_gT, rk_g,
                                                   rwb, rrb, attnb_bf, ent);

  // ---- phase 3: W_o (+cast x=w) + gm GRU gate (z/rx + gate in epilogues) --
  mgemm<64, ACT_RELU, false, MODE_NORM, true, false>
      <<<dim3(8, 32), 256, 0, stream>>>(attnb_bf, nullptr, wt_o, ybuf, nullptr,
                                        w, xw_bf, nullptr, nullptr, nullptr,
                                        1024, 1024);
  mgemm<128, ACT_NONE, true, MODE_ZR, false, true>
      <<<dim3(16, 16), 256, 0, stream>>>(ybuf, xw_bf, wt_gm_zr, zbuf, bias_gm,
                                         w, rxbuf, nullptr, nullptr, nullptr,
                                         2048, 1024);
  mgemm<64, ACT_NONE, false, MODE_GOUT, false, true>
      <<<dim3(8, 32), 256, 0, stream>>>(ybuf, rxbuf, wt_gm_g, o1f, nullptr,
                                        w, nullptr, nullptr, nullptr, zbuf,
                                        2048, 1024);

  // ---- phase 4: FF ----
  ln_kernel<false, true><<<NROWS, 256, 0, stream>>>(o1f, nullptr, ln2_w, ln2_b,
                                                    lnb_bf, o1_bf);
  mgemm<128, ACT_RELU, true, MODE_NORM, true, false>
      <<<dim3(32, 16), 256, 0, stream>>>(lnb_bf, nullptr, wt_ff1, ffh_bf,
                                         ff_b1, nullptr, nullptr, nullptr,
                                         nullptr, nullptr, 1024, DI);
  mgemm<64, ACT_RELU, true, MODE_NORM, true, false>
      <<<dim3(8, 32), 256, 0, stream>>>(ffh_bf, nullptr, wt_ff2, ybuf, ff_b2,
                                        nullptr, nullptr, nullptr, nullptr,
                                        nullptr, DI, 1024);

  // ---- phase 5: gp GRU gate ----
  mgemm<128, ACT_NONE, true, MODE_ZR, false, true>
      <<<dim3(16, 16), 256, 0, stream>>>(ybuf, o1_bf, wt_gp_zr, zbuf, bias_gp,
                                         o1f, rxbuf, nullptr, nullptr, nullptr,
                                         2048, 1024);
  mgemm<64, ACT_NONE, false, MODE_GOUT, false, true>
      <<<dim3(8, 32), 256, 0, stream>>>(ybuf, rxbuf, wt_gp_g, out, nullptr,
                                        o1f, nullptr, nullptr, nullptr, zbuf,
                                        2048, 1024);
}